// Round 7
// baseline (241.410 us; speedup 1.0000x reference)
//
#include <hip/hip_runtime.h>
#include <math.h>

#define NN 1024

typedef __attribute__((ext_vector_type(8))) short bf16x8;
typedef __attribute__((ext_vector_type(4))) float f32x4;
typedef __attribute__((ext_vector_type(4))) unsigned int u32x4;

__device__ __forceinline__ float sigmoidf_(float x) { return 1.0f / (1.0f + __expf(-x)); }

// RNE bf16 round; pack two floats into one dword (lo = a, hi = b)
__device__ __forceinline__ unsigned int pk_bf16(float a, float b) {
    unsigned int ua = __float_as_uint(a), ub = __float_as_uint(b);
    ua += 0x7fffu + ((ua >> 16) & 1u);
    ub += 0x7fffu + ((ub >> 16) & 1u);
    return (ua >> 16) | (ub & 0xffff0000u);
}
__device__ __forceinline__ unsigned short f2bf_rne(float a) {
    unsigned int ua = __float_as_uint(a);
    ua += 0x7fffu + ((ua >> 16) & 1u);
    return (unsigned short)(ua >> 16);
}

struct Ctx {
    bf16x8 w2a0, w2a1, w3a0, w3a1;
    f32x4 b2v0, b2v1, b3v0, b3v1;   // biases folded into MFMA C operand
    float wj8[8];
};

__device__ __forceinline__ void make_ctx(Ctx& c, int p, int q,
    const float* __restrict__ W1, const float* __restrict__ W2,
    const float* __restrict__ b2, const float* __restrict__ W3,
    const float* __restrict__ b3)
{
    union FU { bf16x8 v; unsigned short s[8]; } t0, t1, t2, t3;
#pragma unroll
    for (int jj = 0; jj < 8; jj++) {
        int k = q * 8 + jj;
        t0.s[jj] = f2bf_rne(W2[p * 32 + k]);
        t1.s[jj] = f2bf_rne(W2[(16 + p) * 32 + k]);
        t2.s[jj] = f2bf_rne(W3[p * 32 + k]);
        t3.s[jj] = f2bf_rne(W3[(16 + p) * 32 + k]);
        c.wj8[jj] = W1[k * 67 + 64];
    }
    c.w2a0 = t0.v; c.w2a1 = t1.v; c.w3a0 = t2.v; c.w3a1 = t3.v;
#pragma unroll
    for (int r = 0; r < 4; r++) {
        c.b2v0[r] = b2[q * 4 + r];  c.b2v1[r] = b2[16 + q * 4 + r];
        c.b3v0[r] = b3[q * 4 + r];  c.b3v1[r] = b3[16 + q * 4 + r];
    }
}

// ---------------------------------------------------------------------------
// k_pre: blocks 0..1023 transpose J -> Jt; blocks 1024..1151 init h, u0, v
// ---------------------------------------------------------------------------
__global__ __launch_bounds__(256) void k_pre(
    const float* __restrict__ J, const float* __restrict__ b,
    const float* __restrict__ W1, const float* __restrict__ b1,
    float* __restrict__ Jt, float* __restrict__ h,
    float* __restrict__ u0, float* __restrict__ v)
{
    __shared__ float tile[32][33];
    const int t = blockIdx.x;
    const int tid = threadIdx.x;
    if (t < 1024) {
        int tx = (t & 31) * 32, ty = (t >> 5) * 32;
        int x = tid & 31, y = tid >> 5;   // y in 0..7
#pragma unroll
        for (int r = 0; r < 4; r++)
            tile[y + 8 * r][x] = J[(size_t)(ty + y + 8 * r) * NN + tx + x];
        __syncthreads();
#pragma unroll
        for (int r = 0; r < 4; r++)
            Jt[(size_t)(tx + y + 8 * r) * NN + ty + x] = tile[x][y + 8 * r];
    } else {
        int idx = (t - 1024) * 256 + tid;   // 0..32767
        int row = idx >> 5, mm = idx & 31;
        float bi = b[row];
        h[idx]  = 0.f;
        u0[idx] = bi * W1[mm * 67 + 65];
        v[idx]  = fmaf(bi, W1[mm * 67 + 66], b1[mm]);
    }
}

// ---------------------------------------------------------------------------
// k_step: one recurrence step. Primary grid = 1024 blocks (one per j) x 256
// threads (4 waves x 16 tiles of 16 i's). Blocks >=1024 (instrumentation
// launches only) redo j = blockIdx&1023's main loop and skip the tail -> the
// dispatch gets long enough to surface in the rocprof top-5 with counters.
// Tail (GRU + u/v + readout) parallelized across the whole block.
// ---------------------------------------------------------------------------
__global__ __launch_bounds__(256, 4) void k_step(
    const float* __restrict__ Jt, const float* __restrict__ W1,
    const float* __restrict__ W2, const float* __restrict__ b2,
    const float* __restrict__ W3, const float* __restrict__ b3,
    const float* __restrict__ Wih, const float* __restrict__ bih,
    const float* __restrict__ bhh, const float* __restrict__ b,
    const float* __restrict__ b1,
    const float* __restrict__ R1, const float* __restrict__ rb1,
    const float* __restrict__ R2, const float* __restrict__ rb2,
    const float* __restrict__ R3, const float* __restrict__ rb3,
    float* __restrict__ h, float* __restrict__ v,
    const float* __restrict__ ui, float* __restrict__ uo,
    float* __restrict__ out, int do_out)
{
    __shared__ float red[4 * 32];
    __shared__ float hm[64];     // [h ; m]
    __shared__ float gbuf[96];   // gate pre-activations, also readout scratch
    __shared__ float hnb[32];    // h_new
    __shared__ float tb[32];     // readout scratch 2

    const int tid = threadIdx.x;
    const int w = tid >> 6;
    const int l = tid & 63;
    const int p = l & 15;
    const int q = l >> 4;
    const int j = blockIdx.x & 1023;
    const bool primary = (blockIdx.x < 1024);

    Ctx c; make_ctx(c, p, q, W1, W2, b2, W3, b3);
    const float* Jtrow = Jt + (size_t)j * NN;

    float vv[8];
#pragma unroll
    for (int jj = 0; jj < 8; jj++) vv[jj] = v[j * 32 + q * 8 + jj];

    // bpermute byte-addresses for the C->B layout exchange
    const int s0 = (p | ((l & 16) << 1)) << 2;
    const int s1 = s0 + 64;
    const bool qlo = (l & 32) == 0;

    f32x4 acc0 = {0.f, 0.f, 0.f, 0.f}, acc1 = {0.f, 0.f, 0.f, 0.f};

    // ---- depth-2 register prefetch pipeline
    const int ibase = w * 256;
    float  jwA = Jtrow[ibase + p];
    float4 uaA = *(const float4*)(ui + (ibase + p) * 32 + q * 8);
    float4 ubA = *(const float4*)(ui + (ibase + p) * 32 + q * 8 + 4);
    float  jwB = Jtrow[ibase + 16 + p];
    float4 uaB = *(const float4*)(ui + (ibase + 16 + p) * 32 + q * 8);
    float4 ubB = *(const float4*)(ui + (ibase + 16 + p) * 32 + q * 8 + 4);

#pragma unroll 4
    for (int t = 0; t < 16; ++t) {
        float  jw_c;
        float4 ua_c, ub_c;
        if ((t & 1) == 0) { jw_c = jwA; ua_c = uaA; ub_c = ubA; }
        else              { jw_c = jwB; ua_c = uaB; ub_c = ubB; }
        if (t < 14) {
            const int in = ibase + (t + 2) * 16 + p;
            if ((t & 1) == 0) {
                jwA = Jtrow[in];
                uaA = *(const float4*)(ui + in * 32 + q * 8);
                ubA = *(const float4*)(ui + in * 32 + q * 8 + 4);
            } else {
                jwB = Jtrow[in];
                uaB = *(const float4*)(ui + in * 32 + q * 8);
                ubB = *(const float4*)(ui + in * 32 + q * 8 + 4);
            }
        }

        float xr[8];
        xr[0] = fmaxf(fmaf(jw_c, c.wj8[0], ua_c.x + vv[0]), 0.f);
        xr[1] = fmaxf(fmaf(jw_c, c.wj8[1], ua_c.y + vv[1]), 0.f);
        xr[2] = fmaxf(fmaf(jw_c, c.wj8[2], ua_c.z + vv[2]), 0.f);
        xr[3] = fmaxf(fmaf(jw_c, c.wj8[3], ua_c.w + vv[3]), 0.f);
        xr[4] = fmaxf(fmaf(jw_c, c.wj8[4], ub_c.x + vv[4]), 0.f);
        xr[5] = fmaxf(fmaf(jw_c, c.wj8[5], ub_c.y + vv[5]), 0.f);
        xr[6] = fmaxf(fmaf(jw_c, c.wj8[6], ub_c.z + vv[6]), 0.f);
        xr[7] = fmaxf(fmaf(jw_c, c.wj8[7], ub_c.w + vv[7]), 0.f);

        union BU { u32x4 u4; bf16x8 v; unsigned int d[4]; } bx;
#pragma unroll
        for (int cc = 0; cc < 4; cc++) bx.d[cc] = pk_bf16(xr[2 * cc], xr[2 * cc + 1]);

        f32x4 c0 = __builtin_amdgcn_mfma_f32_16x16x32_bf16(c.w2a0, bx.v, c.b2v0, 0, 0, 0);
        f32x4 c1 = __builtin_amdgcn_mfma_f32_16x16x32_bf16(c.w2a1, bx.v, c.b2v1, 0, 0, 0);

        const int d0 = (int)pk_bf16(fmaxf(c0[0], 0.f), fmaxf(c0[1], 0.f));
        const int d1 = (int)pk_bf16(fmaxf(c0[2], 0.f), fmaxf(c0[3], 0.f));
        const int d2 = (int)pk_bf16(fmaxf(c1[0], 0.f), fmaxf(c1[1], 0.f));
        const int d3 = (int)pk_bf16(fmaxf(c1[2], 0.f), fmaxf(c1[3], 0.f));

        const int A0 = __builtin_amdgcn_ds_bpermute(s0, d0);
        const int A1 = __builtin_amdgcn_ds_bpermute(s0, d1);
        const int A2 = __builtin_amdgcn_ds_bpermute(s1, d0);
        const int A3 = __builtin_amdgcn_ds_bpermute(s1, d1);
        const int B0 = __builtin_amdgcn_ds_bpermute(s0, d2);
        const int B1 = __builtin_amdgcn_ds_bpermute(s0, d3);
        const int B2 = __builtin_amdgcn_ds_bpermute(s1, d2);
        const int B3 = __builtin_amdgcn_ds_bpermute(s1, d3);

        union BU yr;
        yr.d[0] = (unsigned)(qlo ? A0 : B0);
        yr.d[1] = (unsigned)(qlo ? A1 : B1);
        yr.d[2] = (unsigned)(qlo ? A2 : B2);
        yr.d[3] = (unsigned)(qlo ? A3 : B3);

        f32x4 e0 = __builtin_amdgcn_mfma_f32_16x16x32_bf16(c.w3a0, yr.v, c.b3v0, 0, 0, 0);
        f32x4 e1 = __builtin_amdgcn_mfma_f32_16x16x32_bf16(c.w3a1, yr.v, c.b3v1, 0, 0, 0);
#pragma unroll
        for (int r = 0; r < 4; r++) {
            acc0[r] += fmaxf(e0[r], 0.f);
            acc1[r] += fmaxf(e1[r], 0.f);
        }
    }

    // reduce over p (lane bits 0..3), then waves via LDS
#pragma unroll
    for (int bit = 1; bit < 16; bit <<= 1) {
#pragma unroll
        for (int r = 0; r < 4; r++) {
            acc0[r] += __shfl_xor(acc0[r], bit);
            acc1[r] += __shfl_xor(acc1[r], bit);
        }
    }
    if (p == 0) {
#pragma unroll
        for (int r = 0; r < 4; r++) {
            red[w * 32 + q * 4 + r]      = acc0[r];
            red[w * 32 + 16 + q * 4 + r] = acc1[r];
        }
    }

    if (!primary) return;   // instrumentation duplicates skip the tail
    __syncthreads();

    // ---- Phase A: hm = [h ; m]
    if (tid < 64) {
        float val;
        if (tid < 32) val = h[j * 32 + tid];
        else {
            int s = tid - 32;
            val = red[s] + red[32 + s] + red[64 + s] + red[96 + s];
        }
        hm[tid] = val;
    }
    __syncthreads();

    // ---- Phase B: gate GEMV, 2 threads per output row (96 rows)
    if (tid < 192) {
        const int row = tid >> 1, half = tid & 1;
        const float* wr = Wih + row * 64 + half * 32;
        const float* hh = hm + half * 32;
        float acc = 0.f;
#pragma unroll
        for (int k4 = 0; k4 < 8; k4++) {
            float4 w4 = *(const float4*)(wr + 4 * k4);
            acc = fmaf(w4.x, hh[4 * k4 + 0], acc);
            acc = fmaf(w4.y, hh[4 * k4 + 1], acc);
            acc = fmaf(w4.z, hh[4 * k4 + 2], acc);
            acc = fmaf(w4.w, hh[4 * k4 + 3], acc);
        }
        acc += __shfl_xor(acc, 1);
        if (half == 0) gbuf[row] = acc + bih[row];
    }
    __syncthreads();

    // ---- Phase C: gates -> h_new
    if (tid < 32) {
        const int s = tid;
        float r = sigmoidf_(gbuf[s] + bhh[s]);
        float z = sigmoidf_(gbuf[32 + s] + bhh[32 + s]);
        float n = tanhf(gbuf[64 + s] + r * bhh[64 + s]);
        float hn_ = (1.0f - z) * n;
        hnb[s] = hn_;
        h[j * 32 + s] = hn_;
    }
    __syncthreads();

    // ---- Phase D: u/v refresh, 64 threads
    if (tid < 64) {
        const int s = tid & 31;
        const bool isV = tid >= 32;
        const float bj = b[j];
        const float* wr = W1 + s * 67 + (isV ? 32 : 0);
        float acc = isV ? fmaf(bj, W1[s * 67 + 66], b1[s]) : bj * W1[s * 67 + 65];
#pragma unroll
        for (int k = 0; k < 32; k++) acc = fmaf(wr[k], hnb[k], acc);
        if (isV) v[j * 32 + s] = acc;
        else     uo[j * 32 + s] = acc;
    }

    // ---- Phase E: readout (final step only)
    if (do_out) {
        __syncthreads();
        if (tid < 32) {
            float a = rb1[tid];
            const float* rr = R1 + tid * 32;
#pragma unroll
            for (int k4 = 0; k4 < 8; k4++) {
                float4 w4 = *(const float4*)(rr + 4 * k4);
                a = fmaf(w4.x, hnb[4 * k4 + 0], a);
                a = fmaf(w4.y, hnb[4 * k4 + 1], a);
                a = fmaf(w4.z, hnb[4 * k4 + 2], a);
                a = fmaf(w4.w, hnb[4 * k4 + 3], a);
            }
            gbuf[tid] = fmaxf(a, 0.f);
        }
        __syncthreads();
        if (tid < 32) {
            float a = rb2[tid];
            const float* rr = R2 + tid * 32;
#pragma unroll
            for (int k4 = 0; k4 < 8; k4++) {
                float4 w4 = *(const float4*)(rr + 4 * k4);
                a = fmaf(w4.x, gbuf[4 * k4 + 0], a);
                a = fmaf(w4.y, gbuf[4 * k4 + 1], a);
                a = fmaf(w4.z, gbuf[4 * k4 + 2], a);
                a = fmaf(w4.w, gbuf[4 * k4 + 3], a);
            }
            tb[tid] = fmaxf(a, 0.f);
        }
        __syncthreads();
        if (tid < 2) {
            float a = rb3[tid];
            const float* rr = R3 + tid * 32;
#pragma unroll
            for (int k = 0; k < 32; k++) a = fmaf(rr[k], tb[k], a);
            out[j * 2 + tid] = sigmoidf_(fmaxf(a, 0.f));
        }
    }
}

// ---------------------------------------------------------------------------
extern "C" void kernel_launch(void* const* d_in, const int* in_sizes, int n_in,
                              void* d_out, int out_size, void* d_ws, size_t ws_size,
                              hipStream_t stream)
{
    const float* J   = (const float*)d_in[0];
    const float* b   = (const float*)d_in[1];
    const float* W1  = (const float*)d_in[2];
    const float* b1  = (const float*)d_in[3];
    const float* W2  = (const float*)d_in[4];
    const float* b2  = (const float*)d_in[5];
    const float* W3  = (const float*)d_in[6];
    const float* b3  = (const float*)d_in[7];
    const float* Wih = (const float*)d_in[8];
    const float* bih = (const float*)d_in[9];
    const float* bhh = (const float*)d_in[10];
    const float* R1  = (const float*)d_in[11];
    const float* rb1 = (const float*)d_in[12];
    const float* R2  = (const float*)d_in[13];
    const float* rb2 = (const float*)d_in[14];
    const float* R3  = (const float*)d_in[15];
    const float* rb3 = (const float*)d_in[16];

    float* out = (float*)d_out;
    float* ws  = (float*)d_ws;
    float* h  = ws;
    float* v  = ws + 32768;
    float* u0 = ws + 65536;
    float* u1 = ws + 98304;
    float* Jt = ws + 131072;

    k_pre<<<1152, 256, 0, stream>>>(J, b, W1, b1, Jt, h, u0, v);
    for (int s = 0; s < 5; s++) {
        const float* ui = (s & 1) ? u1 : u0;
        float*       uo = (s & 1) ? u0 : u1;
        // step 0 launches 2x blocks: blocks >=1024 duplicate the main loop and
        // skip the tail, pushing this dispatch into the rocprof top-5.
        int grid = (s == 0) ? 2048 : 1024;
        k_step<<<grid, 256, 0, stream>>>(Jt, W1, W2, b2, W3, b3, Wih, bih,
                                         bhh, b, b1, R1, rb1, R2, rb2, R3,
                                         rb3, h, v, ui, uo, out,
                                         (s == 4) ? 1 : 0);
    }
}

// Round 8
// 220.534 us; speedup vs baseline: 1.0947x; 1.0947x over previous
//
#include <hip/hip_runtime.h>
#include <hip/hip_cooperative_groups.h>
#include <math.h>

namespace cg = cooperative_groups;

#define NN 1024

typedef __attribute__((ext_vector_type(8))) short bf16x8;
typedef __attribute__((ext_vector_type(4))) float f32x4;
typedef __attribute__((ext_vector_type(4))) unsigned int u32x4;

__device__ __forceinline__ float sigmoidf_(float x) { return 1.0f / (1.0f + __expf(-x)); }

// bf16 pair pack, round-half-away-from-zero: 3 VALU ops (2 add + v_perm).
// Differs from RNE only at exact ties (1 ulp, p~2^-16).  lo = a, hi = b.
__device__ __forceinline__ unsigned int pk2(float a, float b) {
    return __builtin_amdgcn_perm(__float_as_uint(a) + 0x8000u,
                                 __float_as_uint(b) + 0x8000u, 0x03020706u);
}
__device__ __forceinline__ unsigned short f2bf_rne(float a) {
    unsigned int ua = __float_as_uint(a);
    ua += 0x7fffu + ((ua >> 16) & 1u);
    return (unsigned short)(ua >> 16);
}

struct Ctx {
    bf16x8 w2a0, w2a1, w3a0, w3a1;
    f32x4 b2v0, b2v1, b3v0, b3v1;   // biases folded into MFMA C operand
    float wj8[8];
};

__device__ __forceinline__ void make_ctx(Ctx& c, int p, int q,
    const float* __restrict__ W1, const float* __restrict__ W2,
    const float* __restrict__ b2, const float* __restrict__ W3,
    const float* __restrict__ b3)
{
    union FU { bf16x8 v; unsigned short s[8]; } t0, t1, t2, t3;
#pragma unroll
    for (int jj = 0; jj < 8; jj++) {
        int k = q * 8 + jj;
        t0.s[jj] = f2bf_rne(W2[p * 32 + k]);
        t1.s[jj] = f2bf_rne(W2[(16 + p) * 32 + k]);
        t2.s[jj] = f2bf_rne(W3[p * 32 + k]);
        t3.s[jj] = f2bf_rne(W3[(16 + p) * 32 + k]);
        c.wj8[jj] = W1[k * 67 + 64];
    }
    c.w2a0 = t0.v; c.w2a1 = t1.v; c.w3a0 = t2.v; c.w3a1 = t3.v;
#pragma unroll
    for (int r = 0; r < 4; r++) {
        c.b2v0[r] = b2[q * 4 + r];  c.b2v1[r] = b2[16 + q * 4 + r];
        c.b3v0[r] = b3[q * 4 + r];  c.b3v1[r] = b3[16 + q * 4 + r];
    }
}

// 16 tiles of 16 i's (one wave's share), depth-2 register prefetch.
__device__ __forceinline__ void main16(const Ctx& c,
    const float* __restrict__ Jtrow, const float* __restrict__ ui,
    const float* vv, int w, int p, int q, int s0, int s1, bool qlo,
    f32x4& acc0, f32x4& acc1)
{
    const int ibase = w * 256;
    float  jwA = Jtrow[ibase + p];
    float4 uaA = *(const float4*)(ui + (ibase + p) * 32 + q * 8);
    float4 ubA = *(const float4*)(ui + (ibase + p) * 32 + q * 8 + 4);
    float  jwB = Jtrow[ibase + 16 + p];
    float4 uaB = *(const float4*)(ui + (ibase + 16 + p) * 32 + q * 8);
    float4 ubB = *(const float4*)(ui + (ibase + 16 + p) * 32 + q * 8 + 4);

#pragma unroll 4
    for (int t = 0; t < 16; ++t) {
        float  jw_c;
        float4 ua_c, ub_c;
        if ((t & 1) == 0) { jw_c = jwA; ua_c = uaA; ub_c = ubA; }
        else              { jw_c = jwB; ua_c = uaB; ub_c = ubB; }
        if (t < 14) {
            const int in = ibase + (t + 2) * 16 + p;
            if ((t & 1) == 0) {
                jwA = Jtrow[in];
                uaA = *(const float4*)(ui + in * 32 + q * 8);
                ubA = *(const float4*)(ui + in * 32 + q * 8 + 4);
            } else {
                jwB = Jtrow[in];
                uaB = *(const float4*)(ui + in * 32 + q * 8);
                ubB = *(const float4*)(ui + in * 32 + q * 8 + 4);
            }
        }

        float xr[8];
        xr[0] = fmaxf(fmaf(jw_c, c.wj8[0], ua_c.x + vv[0]), 0.f);
        xr[1] = fmaxf(fmaf(jw_c, c.wj8[1], ua_c.y + vv[1]), 0.f);
        xr[2] = fmaxf(fmaf(jw_c, c.wj8[2], ua_c.z + vv[2]), 0.f);
        xr[3] = fmaxf(fmaf(jw_c, c.wj8[3], ua_c.w + vv[3]), 0.f);
        xr[4] = fmaxf(fmaf(jw_c, c.wj8[4], ub_c.x + vv[4]), 0.f);
        xr[5] = fmaxf(fmaf(jw_c, c.wj8[5], ub_c.y + vv[5]), 0.f);
        xr[6] = fmaxf(fmaf(jw_c, c.wj8[6], ub_c.z + vv[6]), 0.f);
        xr[7] = fmaxf(fmaf(jw_c, c.wj8[7], ub_c.w + vv[7]), 0.f);

        union BU { u32x4 u4; bf16x8 v; unsigned int d[4]; } bx;
        bx.d[0] = pk2(xr[0], xr[1]);
        bx.d[1] = pk2(xr[2], xr[3]);
        bx.d[2] = pk2(xr[4], xr[5]);
        bx.d[3] = pk2(xr[6], xr[7]);

        f32x4 c0 = __builtin_amdgcn_mfma_f32_16x16x32_bf16(c.w2a0, bx.v, c.b2v0, 0, 0, 0);
        f32x4 c1 = __builtin_amdgcn_mfma_f32_16x16x32_bf16(c.w2a1, bx.v, c.b2v1, 0, 0, 0);

        const int d0 = (int)pk2(fmaxf(c0[0], 0.f), fmaxf(c0[1], 0.f));
        const int d1 = (int)pk2(fmaxf(c0[2], 0.f), fmaxf(c0[3], 0.f));
        const int d2 = (int)pk2(fmaxf(c1[0], 0.f), fmaxf(c1[1], 0.f));
        const int d3 = (int)pk2(fmaxf(c1[2], 0.f), fmaxf(c1[3], 0.f));

        const int A0 = __builtin_amdgcn_ds_bpermute(s0, d0);
        const int A1 = __builtin_amdgcn_ds_bpermute(s0, d1);
        const int A2 = __builtin_amdgcn_ds_bpermute(s1, d0);
        const int A3 = __builtin_amdgcn_ds_bpermute(s1, d1);
        const int B0 = __builtin_amdgcn_ds_bpermute(s0, d2);
        const int B1 = __builtin_amdgcn_ds_bpermute(s0, d3);
        const int B2 = __builtin_amdgcn_ds_bpermute(s1, d2);
        const int B3 = __builtin_amdgcn_ds_bpermute(s1, d3);

        union BU yr;
        yr.d[0] = (unsigned)(qlo ? A0 : B0);
        yr.d[1] = (unsigned)(qlo ? A1 : B1);
        yr.d[2] = (unsigned)(qlo ? A2 : B2);
        yr.d[3] = (unsigned)(qlo ? A3 : B3);

        f32x4 e0 = __builtin_amdgcn_mfma_f32_16x16x32_bf16(c.w3a0, yr.v, c.b3v0, 0, 0, 0);
        f32x4 e1 = __builtin_amdgcn_mfma_f32_16x16x32_bf16(c.w3a1, yr.v, c.b3v1, 0, 0, 0);
#pragma unroll
        for (int r = 0; r < 4; r++) {
            acc0[r] += fmaxf(e0[r], 0.f);
            acc1[r] += fmaxf(e1[r], 0.f);
        }
    }
}

// ---------------------------------------------------------------------------
// k_pre: blocks 0..1023 transpose J -> Jt; blocks 1024..1151 init h, u0, v
// ---------------------------------------------------------------------------
__global__ __launch_bounds__(256) void k_pre(
    const float* __restrict__ J, const float* __restrict__ b,
    const float* __restrict__ W1, const float* __restrict__ b1,
    float* __restrict__ Jt, float* __restrict__ h,
    float* __restrict__ u0, float* __restrict__ v)
{
    __shared__ float tile[32][33];
    const int t = blockIdx.x;
    const int tid = threadIdx.x;
    if (t < 1024) {
        int tx = (t & 31) * 32, ty = (t >> 5) * 32;
        int x = tid & 31, y = tid >> 5;
#pragma unroll
        for (int r = 0; r < 4; r++)
            tile[y + 8 * r][x] = J[(size_t)(ty + y + 8 * r) * NN + tx + x];
        __syncthreads();
#pragma unroll
        for (int r = 0; r < 4; r++)
            Jt[(size_t)(tx + y + 8 * r) * NN + ty + x] = tile[x][y + 8 * r];
    } else {
        int idx = (t - 1024) * 256 + tid;
        int row = idx >> 5, mm = idx & 31;
        float bi = b[row];
        h[idx]  = 0.f;
        u0[idx] = bi * W1[mm * 67 + 65];
        v[idx]  = fmaf(bi, W1[mm * 67 + 66], b1[mm]);
    }
}

// ---------------------------------------------------------------------------
// k_coop: one persistent block per j, 256 threads, 4 blocks/CU (16 waves/CU).
// All 5 steps in one launch; 1 grid.sync per step boundary (4 total).
// h, v block-local in LDS; tail weights LDS-resident for all steps.
// ---------------------------------------------------------------------------
__global__ __launch_bounds__(256, 4) void k_coop(
    const float* __restrict__ Jt, const float* __restrict__ W1,
    const float* __restrict__ W2, const float* __restrict__ b2,
    const float* __restrict__ W3, const float* __restrict__ b3,
    const float* __restrict__ Wih, const float* __restrict__ bih,
    const float* __restrict__ bhh, const float* __restrict__ b,
    const float* __restrict__ b1,
    const float* __restrict__ R1, const float* __restrict__ rb1,
    const float* __restrict__ R2, const float* __restrict__ rb2,
    const float* __restrict__ R3, const float* __restrict__ rb3,
    float* __restrict__ u0, float* __restrict__ u1, float* __restrict__ out)
{
    __shared__ float WihT[64 * 96];   // transposed: WihT[k][row], 24.0 KB
    __shared__ float W1L[32 * 67];    // 8.4 KB
    __shared__ float bihL[96], bhhL[96], b1L[32];
    __shared__ float red[4 * 32];
    __shared__ float hm[64], gbuf[96], hnb[32], tb[32];
    __shared__ float hbuf[32], vbuf[32];

    const int tid = threadIdx.x;
    const int w = tid >> 6;
    const int l = tid & 63;
    const int p = l & 15;
    const int q = l >> 4;
    const int j = blockIdx.x;
    const float bj = b[j];

    cg::grid_group grid = cg::this_grid();

    Ctx c; make_ctx(c, p, q, W1, W2, b2, W3, b3);
    const float* Jtrow = Jt + (size_t)j * NN;

    // ---- one-time LDS staging of tail weights ----
    for (int t = tid; t < 96 * 64; t += 256)
        WihT[(t & 63) * 96 + (t >> 6)] = Wih[t];   // coalesced read, stride-96 write
    for (int t = tid; t < 32 * 67; t += 256) W1L[t] = W1[t];
    if (tid < 96) { bihL[tid] = bih[tid]; bhhL[tid] = bhh[tid]; }
    if (tid < 32) {
        b1L[tid]  = b1[tid];
        hbuf[tid] = 0.f;
        vbuf[tid] = fmaf(bj, W1[tid * 67 + 66], b1[tid]);
    }
    __syncthreads();

    // bpermute byte-addresses for the C->B layout exchange
    const int s0 = (p | ((l & 16) << 1)) << 2;
    const int s1 = s0 + 64;
    const bool qlo = (l & 32) == 0;

    for (int step = 0; step < 5; ++step) {
        const float* ui = (step & 1) ? u1 : u0;
        float*       uo = (step & 1) ? u0 : u1;

        float vv[8];
#pragma unroll
        for (int jj = 0; jj < 8; jj++) vv[jj] = vbuf[q * 8 + jj];

        f32x4 acc0 = {0.f, 0.f, 0.f, 0.f}, acc1 = {0.f, 0.f, 0.f, 0.f};
        main16(c, Jtrow, ui, vv, w, p, q, s0, s1, qlo, acc0, acc1);

#pragma unroll
        for (int bit = 1; bit < 16; bit <<= 1) {
#pragma unroll
            for (int r = 0; r < 4; r++) {
                acc0[r] += __shfl_xor(acc0[r], bit);
                acc1[r] += __shfl_xor(acc1[r], bit);
            }
        }
        if (p == 0) {
#pragma unroll
            for (int r = 0; r < 4; r++) {
                red[w * 32 + q * 4 + r]      = acc0[r];
                red[w * 32 + 16 + q * 4 + r] = acc1[r];
            }
        }
        __syncthreads();

        // Phase A: hm = [h ; m]
        if (tid < 64) {
            float val;
            if (tid < 32) val = hbuf[tid];
            else {
                int s = tid - 32;
                val = red[s] + red[32 + s] + red[64 + s] + red[96 + s];
            }
            hm[tid] = val;
        }
        __syncthreads();

        // Phase B: gate GEMV from LDS (conflict-free: WihT stride 96 = 0 mod 32)
        if (tid < 192) {
            const int row = tid >> 1, half = tid & 1;
            float acc = 0.f;
#pragma unroll 8
            for (int k = 0; k < 32; k++)
                acc = fmaf(WihT[(half * 32 + k) * 96 + row], hm[half * 32 + k], acc);
            acc += __shfl_xor(acc, 1);
            if (half == 0) gbuf[row] = acc + bihL[row];
        }
        __syncthreads();

        // Phase C: gates -> h_new
        if (tid < 32) {
            const int s = tid;
            float r = sigmoidf_(gbuf[s] + bhhL[s]);
            float z = sigmoidf_(gbuf[32 + s] + bhhL[32 + s]);
            float n = tanhf(gbuf[64 + s] + r * bhhL[64 + s]);
            float hn_ = (1.0f - z) * n;
            hnb[s] = hn_;
            hbuf[s] = hn_;
        }
        __syncthreads();

        // Phase D: u/v refresh (u -> global ping-pong, v -> LDS)
        if (tid < 64) {
            const int s = tid & 31;
            const bool isV = tid >= 32;
            const float* wr = W1L + s * 67 + (isV ? 32 : 0);
            float acc = isV ? fmaf(bj, W1L[s * 67 + 66], b1L[s]) : bj * W1L[s * 67 + 65];
#pragma unroll 8
            for (int k = 0; k < 32; k++) acc = fmaf(wr[k], hnb[k], acc);
            if (isV) vbuf[s] = acc;
            else     uo[j * 32 + s] = acc;
        }

        if (step < 4) {
            __threadfence();   // uo visible device-wide before the barrier
            grid.sync();       // also block-syncs: vbuf/hbuf safe for next step
        }
    }

    // ---- readout (block-local h) ----
    __syncthreads();
    if (tid < 32) {
        float a = rb1[tid];
        const float* rr = R1 + tid * 32;
#pragma unroll 8
        for (int k = 0; k < 32; k++) a = fmaf(rr[k], hnb[k], a);
        gbuf[tid] = fmaxf(a, 0.f);
    }
    __syncthreads();
    if (tid < 32) {
        float a = rb2[tid];
        const float* rr = R2 + tid * 32;
#pragma unroll 8
        for (int k = 0; k < 32; k++) a = fmaf(rr[k], gbuf[k], a);
        tb[tid] = fmaxf(a, 0.f);
    }
    __syncthreads();
    if (tid < 2) {
        float a = rb3[tid];
        const float* rr = R3 + tid * 32;
#pragma unroll 8
        for (int k = 0; k < 32; k++) a = fmaf(rr[k], tb[k], a);
        out[j * 2 + tid] = sigmoidf_(fmaxf(a, 0.f));
    }
}

// ---------------------------------------------------------------------------
// k_step (fallback multi-launch path, r7 structure + cheap pack)
// ---------------------------------------------------------------------------
__global__ __launch_bounds__(256, 4) void k_step(
    const float* __restrict__ Jt, const float* __restrict__ W1,
    const float* __restrict__ W2, const float* __restrict__ b2,
    const float* __restrict__ W3, const float* __restrict__ b3,
    const float* __restrict__ Wih, const float* __restrict__ bih,
    const float* __restrict__ bhh, const float* __restrict__ b,
    const float* __restrict__ b1,
    const float* __restrict__ R1, const float* __restrict__ rb1,
    const float* __restrict__ R2, const float* __restrict__ rb2,
    const float* __restrict__ R3, const float* __restrict__ rb3,
    float* __restrict__ h, float* __restrict__ v,
    const float* __restrict__ ui, float* __restrict__ uo,
    float* __restrict__ out, int do_out)
{
    __shared__ float red[4 * 32];
    __shared__ float hm[64], gbuf[96], hnb[32], tb[32];

    const int tid = threadIdx.x;
    const int w = tid >> 6;
    const int l = tid & 63;
    const int p = l & 15;
    const int q = l >> 4;
    const int j = blockIdx.x;

    Ctx c; make_ctx(c, p, q, W1, W2, b2, W3, b3);
    const float* Jtrow = Jt + (size_t)j * NN;

    float vv[8];
#pragma unroll
    for (int jj = 0; jj < 8; jj++) vv[jj] = v[j * 32 + q * 8 + jj];

    const int s0 = (p | ((l & 16) << 1)) << 2;
    const int s1 = s0 + 64;
    const bool qlo = (l & 32) == 0;

    f32x4 acc0 = {0.f, 0.f, 0.f, 0.f}, acc1 = {0.f, 0.f, 0.f, 0.f};
    main16(c, Jtrow, ui, vv, w, p, q, s0, s1, qlo, acc0, acc1);

#pragma unroll
    for (int bit = 1; bit < 16; bit <<= 1) {
#pragma unroll
        for (int r = 0; r < 4; r++) {
            acc0[r] += __shfl_xor(acc0[r], bit);
            acc1[r] += __shfl_xor(acc1[r], bit);
        }
    }
    if (p == 0) {
#pragma unroll
        for (int r = 0; r < 4; r++) {
            red[w * 32 + q * 4 + r]      = acc0[r];
            red[w * 32 + 16 + q * 4 + r] = acc1[r];
        }
    }
    __syncthreads();

    if (tid < 64) {
        float val;
        if (tid < 32) val = h[j * 32 + tid];
        else {
            int s = tid - 32;
            val = red[s] + red[32 + s] + red[64 + s] + red[96 + s];
        }
        hm[tid] = val;
    }
    __syncthreads();

    if (tid < 192) {
        const int row = tid >> 1, half = tid & 1;
        const float* wr = Wih + row * 64 + half * 32;
        const float* hh = hm + half * 32;
        float acc = 0.f;
#pragma unroll
        for (int k4 = 0; k4 < 8; k4++) {
            float4 w4 = *(const float4*)(wr + 4 * k4);
            acc = fmaf(w4.x, hh[4 * k4 + 0], acc);
            acc = fmaf(w4.y, hh[4 * k4 + 1], acc);
            acc = fmaf(w4.z, hh[4 * k4 + 2], acc);
            acc = fmaf(w4.w, hh[4 * k4 + 3], acc);
        }
        acc += __shfl_xor(acc, 1);
        if (half == 0) gbuf[row] = acc + bih[row];
    }
    __syncthreads();

    if (tid < 32) {
        const int s = tid;
        float r = sigmoidf_(gbuf[s] + bhh[s]);
        float z = sigmoidf_(gbuf[32 + s] + bhh[32 + s]);
        float n = tanhf(gbuf[64 + s] + r * bhh[64 + s]);
        float hn_ = (1.0f - z) * n;
        hnb[s] = hn_;
        h[j * 32 + s] = hn_;
    }
    __syncthreads();

    if (tid < 64) {
        const int s = tid & 31;
        const bool isV = tid >= 32;
        const float bj = b[j];
        const float* wr = W1 + s * 67 + (isV ? 32 : 0);
        float acc = isV ? fmaf(bj, W1[s * 67 + 66], b1[s]) : bj * W1[s * 67 + 65];
#pragma unroll
        for (int k = 0; k < 32; k++) acc = fmaf(wr[k], hnb[k], acc);
        if (isV) v[j * 32 + s] = acc;
        else     uo[j * 32 + s] = acc;
    }

    if (do_out) {
        __syncthreads();
        if (tid < 32) {
            float a = rb1[tid];
            const float* rr = R1 + tid * 32;
#pragma unroll 8
            for (int k = 0; k < 32; k++) a = fmaf(rr[k], hnb[k], a);
            gbuf[tid] = fmaxf(a, 0.f);
        }
        __syncthreads();
        if (tid < 32) {
            float a = rb2[tid];
            const float* rr = R2 + tid * 32;
#pragma unroll 8
            for (int k = 0; k < 32; k++) a = fmaf(rr[k], gbuf[k], a);
            tb[tid] = fmaxf(a, 0.f);
        }
        __syncthreads();
        if (tid < 2) {
            float a = rb3[tid];
            const float* rr = R3 + tid * 32;
#pragma unroll 8
            for (int k = 0; k < 32; k++) a = fmaf(rr[k], tb[k], a);
            out[j * 2 + tid] = sigmoidf_(fmaxf(a, 0.f));
        }
    }
}

// ---------------------------------------------------------------------------
extern "C" void kernel_launch(void* const* d_in, const int* in_sizes, int n_in,
                              void* d_out, int out_size, void* d_ws, size_t ws_size,
                              hipStream_t stream)
{
    const float* J   = (const float*)d_in[0];
    const float* b   = (const float*)d_in[1];
    const float* W1  = (const float*)d_in[2];
    const float* b1  = (const float*)d_in[3];
    const float* W2  = (const float*)d_in[4];
    const float* b2  = (const float*)d_in[5];
    const float* W3  = (const float*)d_in[6];
    const float* b3  = (const float*)d_in[7];
    const float* Wih = (const float*)d_in[8];
    const float* bih = (const float*)d_in[9];
    const float* bhh = (const float*)d_in[10];
    const float* R1  = (const float*)d_in[11];
    const float* rb1 = (const float*)d_in[12];
    const float* R2  = (const float*)d_in[13];
    const float* rb2 = (const float*)d_in[14];
    const float* R3  = (const float*)d_in[15];
    const float* rb3 = (const float*)d_in[16];

    float* out = (float*)d_out;
    float* ws  = (float*)d_ws;
    float* h  = ws;
    float* v  = ws + 32768;
    float* u0 = ws + 65536;
    float* u1 = ws + 98304;
    float* Jt = ws + 131072;

    k_pre<<<1152, 256, 0, stream>>>(J, b, W1, b1, Jt, h, u0, v);

    int mb = 0;
    bool coop =
        (hipOccupancyMaxActiveBlocksPerMultiprocessor(
             &mb, reinterpret_cast<const void*>(&k_coop), 256, 0) == hipSuccess) &&
        (mb >= 4);
    if (coop) {
        void* cargs[] = { (void*)&Jt, (void*)&W1, (void*)&W2, (void*)&b2,
                          (void*)&W3, (void*)&b3, (void*)&Wih, (void*)&bih,
                          (void*)&bhh, (void*)&b, (void*)&b1,
                          (void*)&R1, (void*)&rb1, (void*)&R2, (void*)&rb2,
                          (void*)&R3, (void*)&rb3,
                          (void*)&u0, (void*)&u1, (void*)&out };
        if (hipLaunchCooperativeKernel(reinterpret_cast<const void*>(&k_coop),
                                       dim3(1024), dim3(256), cargs, 0, stream)
            != hipSuccess)
            coop = false;
    }
    if (!coop) {
        for (int s = 0; s < 5; s++) {
            const float* ui = (s & 1) ? u1 : u0;
            float*       uo = (s & 1) ? u0 : u1;
            k_step<<<1024, 256, 0, stream>>>(Jt, W1, W2, b2, W3, b3, Wih, bih,
                                             bhh, b, b1, R1, rb1, R2, rb2, R3,
                                             rb3, h, v, ui, uo, out,
                                             (s == 4) ? 1 : 0);
        }
    }
}

// Round 9
// 200.889 us; speedup vs baseline: 1.2017x; 1.0978x over previous
//
#include <hip/hip_runtime.h>
#include <math.h>

#define NN 1024

typedef __attribute__((ext_vector_type(8))) short bf16x8;
typedef __attribute__((ext_vector_type(4))) float f32x4;
typedef __attribute__((ext_vector_type(4))) unsigned int u32x4;

__device__ __forceinline__ float sigmoidf_(float x) { return 1.0f / (1.0f + __expf(-x)); }

// bf16 pair pack, round-half-away-from-zero: 3 VALU ops. lo = a, hi = b.
__device__ __forceinline__ unsigned int pk2(float a, float b) {
    return __builtin_amdgcn_perm(__float_as_uint(a) + 0x8000u,
                                 __float_as_uint(b) + 0x8000u, 0x03020706u);
}
__device__ __forceinline__ unsigned short f2bf_rne(float a) {
    unsigned int ua = __float_as_uint(a);
    ua += 0x7fffu + ((ua >> 16) & 1u);
    return (unsigned short)(ua >> 16);
}

// cfg layout (floats, per-lane SoA; each array 64 lanes x 4 dwords = 256):
//  +0    w2a0 | +256 w2a1 | +512 w3a0 | +768 w3a1
//  +1024 b2v0 | +1280 b2v1 | +1536 b3v0 | +1792 b3v1
//  +2048 wj lo | +2304 wj hi          (total 2560 floats = 10 KB)
#define CFG_FLOATS 2560

// ---------------------------------------------------------------------------
// k_pre: blocks 0..1023 transpose J -> Jt; 1024..1151 init h,u0,v;
//        block 1152 precomputes the per-lane MFMA context into cfg.
// ---------------------------------------------------------------------------
__global__ __launch_bounds__(256) void k_pre(
    const float* __restrict__ J, const float* __restrict__ b,
    const float* __restrict__ W1, const float* __restrict__ b1,
    const float* __restrict__ W2, const float* __restrict__ b2,
    const float* __restrict__ W3, const float* __restrict__ b3,
    float* __restrict__ Jt, float* __restrict__ h,
    float* __restrict__ u0, float* __restrict__ v, float* __restrict__ cfg)
{
    __shared__ float tile[32][33];
    const int t = blockIdx.x;
    const int tid = threadIdx.x;
    if (t < 1024) {
        int tx = (t & 31) * 32, ty = (t >> 5) * 32;
        int x = tid & 31, y = tid >> 5;
#pragma unroll
        for (int r = 0; r < 4; r++)
            tile[y + 8 * r][x] = J[(size_t)(ty + y + 8 * r) * NN + tx + x];
        __syncthreads();
#pragma unroll
        for (int r = 0; r < 4; r++)
            Jt[(size_t)(tx + y + 8 * r) * NN + ty + x] = tile[x][y + 8 * r];
    } else if (t < 1152) {
        int idx = (t - 1024) * 256 + tid;
        int row = idx >> 5, mm = idx & 31;
        float bi = b[row];
        h[idx]  = 0.f;
        u0[idx] = bi * W1[mm * 67 + 65];
        v[idx]  = fmaf(bi, W1[mm * 67 + 66], b1[mm]);
    } else if (tid < 64) {
        const int l = tid, p = l & 15, q = l >> 4;
        union FU { unsigned int d[4]; unsigned short s[8]; } t0, t1, t2, t3;
        float wj[8];
#pragma unroll
        for (int jj = 0; jj < 8; jj++) {
            int k = q * 8 + jj;
            t0.s[jj] = f2bf_rne(W2[p * 32 + k]);
            t1.s[jj] = f2bf_rne(W2[(16 + p) * 32 + k]);
            t2.s[jj] = f2bf_rne(W3[p * 32 + k]);
            t3.s[jj] = f2bf_rne(W3[(16 + p) * 32 + k]);
            wj[jj] = W1[k * 67 + 64];
        }
        u32x4* cw = (u32x4*)cfg;
        cw[l]       = *(u32x4*)t0.d;
        cw[64 + l]  = *(u32x4*)t1.d;
        cw[128 + l] = *(u32x4*)t2.d;
        cw[192 + l] = *(u32x4*)t3.d;
        f32x4* cf = (f32x4*)(cfg + 1024);
        f32x4 v0, v1, v2, v3;
#pragma unroll
        for (int r = 0; r < 4; r++) {
            v0[r] = b2[q * 4 + r];  v1[r] = b2[16 + q * 4 + r];
            v2[r] = b3[q * 4 + r];  v3[r] = b3[16 + q * 4 + r];
        }
        cf[l] = v0; cf[64 + l] = v1; cf[128 + l] = v2; cf[192 + l] = v3;
        f32x4* cj = (f32x4*)(cfg + 2048);
        f32x4 wlo, whi;
#pragma unroll
        for (int r = 0; r < 4; r++) { wlo[r] = wj[r]; whi[r] = wj[4 + r]; }
        cj[l] = wlo; cj[64 + l] = whi;
    }
}

// ---------------------------------------------------------------------------
// k_step: one recurrence step. 1024 blocks (one per j) x 256 threads
// (4 waves x 16 tiles of 16 i's).  Context via 10 coalesced 16B loads from
// cfg (precomputed in k_pre) -- no scattered W2/W3/W1 prologue loads.
// Tail (GRU + u/v + readout) parallelized across the block.
// ---------------------------------------------------------------------------
__global__ __launch_bounds__(256, 4) void k_step(
    const float* __restrict__ Jt, const float* __restrict__ cfg,
    const float* __restrict__ Wih, const float* __restrict__ bih,
    const float* __restrict__ bhh, const float* __restrict__ b,
    const float* __restrict__ b1, const float* __restrict__ W1,
    const float* __restrict__ R1, const float* __restrict__ rb1,
    const float* __restrict__ R2, const float* __restrict__ rb2,
    const float* __restrict__ R3, const float* __restrict__ rb3,
    float* __restrict__ h, float* __restrict__ v,
    const float* __restrict__ ui, float* __restrict__ uo,
    float* __restrict__ out, int do_out)
{
    __shared__ float red[4 * 32];
    __shared__ float hm[64], gbuf[96], hnb[32], tb[32];

    const int tid = threadIdx.x;
    const int w = tid >> 6;
    const int l = tid & 63;
    const int p = l & 15;
    const int q = l >> 4;
    const int j = blockIdx.x;

    // ---- coalesced per-lane context load (10 x 16B) ----
    union FU { bf16x8 v; u32x4 u4; } w2a0, w2a1, w3a0, w3a1;
    const u32x4* cw = (const u32x4*)cfg;
    w2a0.u4 = cw[l]; w2a1.u4 = cw[64 + l]; w3a0.u4 = cw[128 + l]; w3a1.u4 = cw[192 + l];
    const f32x4* cf = (const f32x4*)(cfg + 1024);
    const f32x4 b2v0 = cf[l], b2v1 = cf[64 + l], b3v0 = cf[128 + l], b3v1 = cf[192 + l];
    const f32x4* cj = (const f32x4*)(cfg + 2048);
    const f32x4 wlo = cj[l], whi = cj[64 + l];
    float wj8[8];
#pragma unroll
    for (int r = 0; r < 4; r++) { wj8[r] = wlo[r]; wj8[4 + r] = whi[r]; }

    float vv[8];
    {
        float4 va = *(const float4*)(v + j * 32 + q * 8);
        float4 vb = *(const float4*)(v + j * 32 + q * 8 + 4);
        vv[0] = va.x; vv[1] = va.y; vv[2] = va.z; vv[3] = va.w;
        vv[4] = vb.x; vv[5] = vb.y; vv[6] = vb.z; vv[7] = vb.w;
    }

    const float* Jtrow = Jt + (size_t)j * NN;
    const int s0 = (p | ((l & 16) << 1)) << 2;
    const int s1 = s0 + 64;
    const bool qlo = (l & 32) == 0;

    f32x4 acc0 = {0.f, 0.f, 0.f, 0.f}, acc1 = {0.f, 0.f, 0.f, 0.f};

    // ---- depth-2 register prefetch pipeline over 16 tiles ----
    const int ibase = w * 256;
    float  jwA = Jtrow[ibase + p];
    float4 uaA = *(const float4*)(ui + (ibase + p) * 32 + q * 8);
    float4 ubA = *(const float4*)(ui + (ibase + p) * 32 + q * 8 + 4);
    float  jwB = Jtrow[ibase + 16 + p];
    float4 uaB = *(const float4*)(ui + (ibase + 16 + p) * 32 + q * 8);
    float4 ubB = *(const float4*)(ui + (ibase + 16 + p) * 32 + q * 8 + 4);

#pragma unroll 4
    for (int t = 0; t < 16; ++t) {
        float  jw_c;
        float4 ua_c, ub_c;
        if ((t & 1) == 0) { jw_c = jwA; ua_c = uaA; ub_c = ubA; }
        else              { jw_c = jwB; ua_c = uaB; ub_c = ubB; }
        if (t < 14) {
            const int in = ibase + (t + 2) * 16 + p;
            if ((t & 1) == 0) {
                jwA = Jtrow[in];
                uaA = *(const float4*)(ui + in * 32 + q * 8);
                ubA = *(const float4*)(ui + in * 32 + q * 8 + 4);
            } else {
                jwB = Jtrow[in];
                uaB = *(const float4*)(ui + in * 32 + q * 8);
                ubB = *(const float4*)(ui + in * 32 + q * 8 + 4);
            }
        }

        float xr[8];
        xr[0] = fmaxf(fmaf(jw_c, wj8[0], ua_c.x + vv[0]), 0.f);
        xr[1] = fmaxf(fmaf(jw_c, wj8[1], ua_c.y + vv[1]), 0.f);
        xr[2] = fmaxf(fmaf(jw_c, wj8[2], ua_c.z + vv[2]), 0.f);
        xr[3] = fmaxf(fmaf(jw_c, wj8[3], ua_c.w + vv[3]), 0.f);
        xr[4] = fmaxf(fmaf(jw_c, wj8[4], ub_c.x + vv[4]), 0.f);
        xr[5] = fmaxf(fmaf(jw_c, wj8[5], ub_c.y + vv[5]), 0.f);
        xr[6] = fmaxf(fmaf(jw_c, wj8[6], ub_c.z + vv[6]), 0.f);
        xr[7] = fmaxf(fmaf(jw_c, wj8[7], ub_c.w + vv[7]), 0.f);

        union BU { u32x4 u4; bf16x8 v; unsigned int d[4]; } bx;
        bx.d[0] = pk2(xr[0], xr[1]);
        bx.d[1] = pk2(xr[2], xr[3]);
        bx.d[2] = pk2(xr[4], xr[5]);
        bx.d[3] = pk2(xr[6], xr[7]);

        f32x4 c0 = __builtin_amdgcn_mfma_f32_16x16x32_bf16(w2a0.v, bx.v, b2v0, 0, 0, 0);
        f32x4 c1 = __builtin_amdgcn_mfma_f32_16x16x32_bf16(w2a1.v, bx.v, b2v1, 0, 0, 0);

        const int d0 = (int)pk2(fmaxf(c0[0], 0.f), fmaxf(c0[1], 0.f));
        const int d1 = (int)pk2(fmaxf(c0[2], 0.f), fmaxf(c0[3], 0.f));
        const int d2 = (int)pk2(fmaxf(c1[0], 0.f), fmaxf(c1[1], 0.f));
        const int d3 = (int)pk2(fmaxf(c1[2], 0.f), fmaxf(c1[3], 0.f));

        const int A0 = __builtin_amdgcn_ds_bpermute(s0, d0);
        const int A1 = __builtin_amdgcn_ds_bpermute(s0, d1);
        const int A2 = __builtin_amdgcn_ds_bpermute(s1, d0);
        const int A3 = __builtin_amdgcn_ds_bpermute(s1, d1);
        const int B0 = __builtin_amdgcn_ds_bpermute(s0, d2);
        const int B1 = __builtin_amdgcn_ds_bpermute(s0, d3);
        const int B2 = __builtin_amdgcn_ds_bpermute(s1, d2);
        const int B3 = __builtin_amdgcn_ds_bpermute(s1, d3);

        union BU yr;
        yr.d[0] = (unsigned)(qlo ? A0 : B0);
        yr.d[1] = (unsigned)(qlo ? A1 : B1);
        yr.d[2] = (unsigned)(qlo ? A2 : B2);
        yr.d[3] = (unsigned)(qlo ? A3 : B3);

        f32x4 e0 = __builtin_amdgcn_mfma_f32_16x16x32_bf16(w3a0.v, yr.v, b3v0, 0, 0, 0);
        f32x4 e1 = __builtin_amdgcn_mfma_f32_16x16x32_bf16(w3a1.v, yr.v, b3v1, 0, 0, 0);
#pragma unroll
        for (int r = 0; r < 4; r++) {
            acc0[r] += fmaxf(e0[r], 0.f);
            acc1[r] += fmaxf(e1[r], 0.f);
        }
    }

    // reduce over p (lane bits 0..3), then waves via LDS
#pragma unroll
    for (int bit = 1; bit < 16; bit <<= 1) {
#pragma unroll
        for (int r = 0; r < 4; r++) {
            acc0[r] += __shfl_xor(acc0[r], bit);
            acc1[r] += __shfl_xor(acc1[r], bit);
        }
    }
    if (p == 0) {
#pragma unroll
        for (int r = 0; r < 4; r++) {
            red[w * 32 + q * 4 + r]      = acc0[r];
            red[w * 32 + 16 + q * 4 + r] = acc1[r];
        }
    }
    __syncthreads();

    // ---- tail: GRU + u/v refresh (+ readout), parallel across block ----
    if (tid < 64) {
        float val;
        if (tid < 32) val = h[j * 32 + tid];
        else {
            int s = tid - 32;
            val = red[s] + red[32 + s] + red[64 + s] + red[96 + s];
        }
        hm[tid] = val;
    }
    __syncthreads();

    if (tid < 192) {
        const int row = tid >> 1, half = tid & 1;
        const float* wr = Wih + row * 64 + half * 32;
        const float* hh = hm + half * 32;
        float acc = 0.f;
#pragma unroll
        for (int k4 = 0; k4 < 8; k4++) {
            float4 w4 = *(const float4*)(wr + 4 * k4);
            acc = fmaf(w4.x, hh[4 * k4 + 0], acc);
            acc = fmaf(w4.y, hh[4 * k4 + 1], acc);
            acc = fmaf(w4.z, hh[4 * k4 + 2], acc);
            acc = fmaf(w4.w, hh[4 * k4 + 3], acc);
        }
        acc += __shfl_xor(acc, 1);
        if (half == 0) gbuf[row] = acc + bih[row];
    }
    __syncthreads();

    if (tid < 32) {
        const int s = tid;
        float r = sigmoidf_(gbuf[s] + bhh[s]);
        float z = sigmoidf_(gbuf[32 + s] + bhh[32 + s]);
        float n = tanhf(gbuf[64 + s] + r * bhh[64 + s]);
        float hn_ = (1.0f - z) * n;
        hnb[s] = hn_;
        h[j * 32 + s] = hn_;
    }
    __syncthreads();

    if (tid < 64) {
        const int s = tid & 31;
        const bool isV = tid >= 32;
        const float bj = b[j];
        const float* wr = W1 + s * 67 + (isV ? 32 : 0);
        float acc = isV ? fmaf(bj, W1[s * 67 + 66], b1[s]) : bj * W1[s * 67 + 65];
#pragma unroll
        for (int k = 0; k < 32; k++) acc = fmaf(wr[k], hnb[k], acc);
        if (isV) v[j * 32 + s] = acc;
        else     uo[j * 32 + s] = acc;
    }

    if (do_out) {
        __syncthreads();
        if (tid < 32) {
            float a = rb1[tid];
            const float* rr = R1 + tid * 32;
#pragma unroll 8
            for (int k = 0; k < 32; k++) a = fmaf(rr[k], hnb[k], a);
            gbuf[tid] = fmaxf(a, 0.f);
        }
        __syncthreads();
        if (tid < 32) {
            float a = rb2[tid];
            const float* rr = R2 + tid * 32;
#pragma unroll 8
            for (int k = 0; k < 32; k++) a = fmaf(rr[k], gbuf[k], a);
            tb[tid] = fmaxf(a, 0.f);
        }
        __syncthreads();
        if (tid < 2) {
            float a = rb3[tid];
            const float* rr = R3 + tid * 32;
#pragma unroll 8
            for (int k = 0; k < 32; k++) a = fmaf(rr[k], tb[k], a);
            out[j * 2 + tid] = sigmoidf_(fmaxf(a, 0.f));
        }
    }
}

// ---------------------------------------------------------------------------
extern "C" void kernel_launch(void* const* d_in, const int* in_sizes, int n_in,
                              void* d_out, int out_size, void* d_ws, size_t ws_size,
                              hipStream_t stream)
{
    const float* J   = (const float*)d_in[0];
    const float* b   = (const float*)d_in[1];
    const float* W1  = (const float*)d_in[2];
    const float* b1  = (const float*)d_in[3];
    const float* W2  = (const float*)d_in[4];
    const float* b2  = (const float*)d_in[5];
    const float* W3  = (const float*)d_in[6];
    const float* b3  = (const float*)d_in[7];
    const float* Wih = (const float*)d_in[8];
    const float* bih = (const float*)d_in[9];
    const float* bhh = (const float*)d_in[10];
    const float* R1  = (const float*)d_in[11];
    const float* rb1 = (const float*)d_in[12];
    const float* R2  = (const float*)d_in[13];
    const float* rb2 = (const float*)d_in[14];
    const float* R3  = (const float*)d_in[15];
    const float* rb3 = (const float*)d_in[16];

    float* out = (float*)d_out;
    float* ws  = (float*)d_ws;
    float* h   = ws;
    float* v   = ws + 32768;
    float* u0  = ws + 65536;
    float* u1  = ws + 98304;
    float* Jt  = ws + 131072;
    float* cfg = ws + 131072 + NN * NN;

    k_pre<<<1153, 256, 0, stream>>>(J, b, W1, b1, W2, b2, W3, b3,
                                    Jt, h, u0, v, cfg);
    for (int s = 0; s < 5; s++) {
        const float* ui = (s & 1) ? u1 : u0;
        float*       uo = (s & 1) ? u0 : u1;
        k_step<<<1024, 256, 0, stream>>>(Jt, cfg, Wih, bih, bhh, b, b1, W1,
                                         R1, rb1, R2, rb2, R3, rb3,
                                         h, v, ui, uo, out, (s == 4) ? 1 : 0);
    }
}